// Round 4
// baseline (1837.533 us; speedup 1.0000x reference)
//
#include <hip/hip_runtime.h>
#include <hip/hip_bf16.h>

// Problem: N=25600 rows, D=640, B=64 batches, H=10 heads, dk=64, SEQ=400.
// head_splitter is a RAW RESHAPE: head (b,h) owns flat range [bh*25600,+25600)
// of each of Q,K,V == x-rows [bh*40, bh*40+40) x all 640 cols.
//   Qblk/Vblk = that range viewed [400][64]; Kblk = same range viewed [64][400].
// vals flat order == output flat order, so each head-block's output range is
// its own 40 rows -> fully block-private pipeline, zero workspace.
//
// DTYPE: reference setup_inputs() is jnp.float32 -> buffers are most likely
// fp32 ("float32 -> const float*" per harness contract). Three bf16-typed
// rounds all NaN'd (fp32 misread as bf16 => NaN-dense garbage), empty kernel
// gave finite absmax => dtype is the prime suspect. We template on FP32 and
// sniff the real dtype on-device from gamma (all ones): first u16 of fp32 1.0f
// is 0x0000, of bf16 1.0 is 0x3F80. Both instantiations launch; wrong one
// early-exits. Internally all compute is bf16 MFMA + fp32 accumulate.

typedef unsigned short u16;
typedef short s8v __attribute__((ext_vector_type(8)));   // 8 bf16 (4 VGPRs)
typedef float f4v __attribute__((ext_vector_type(4)));   // MFMA accumulator

__device__ __forceinline__ float us2f(u16 u) {
    union { float f; unsigned int i; } v; v.i = ((unsigned int)u) << 16; return v.f;
}
__device__ __forceinline__ u16 f2us(float f) {
    __hip_bfloat16 h = __float2bfloat16(f);
    return *reinterpret_cast<u16*>(&h);
}

// Element i of buffer p (dtype per FP32) as float.
template<bool FP32>
__device__ __forceinline__ float ld1(const void* p, size_t i) {
    if (FP32) return ((const float*)p)[i];
    return us2f(((const u16*)p)[i]);
}
// 8 consecutive elements starting at i (16B-aligned in both dtypes) as bf16x8.
template<bool FP32>
__device__ __forceinline__ s8v ld8(const void* p, size_t i) {
    s8v r;
    if (FP32) {
        const float4* q = (const float4*)((const float*)p + i);
        const float4 a = q[0], b = q[1];
        r[0] = (short)f2us(a.x); r[1] = (short)f2us(a.y);
        r[2] = (short)f2us(a.z); r[3] = (short)f2us(a.w);
        r[4] = (short)f2us(b.x); r[5] = (short)f2us(b.y);
        r[6] = (short)f2us(b.z); r[7] = (short)f2us(b.w);
    } else {
        r = *(const s8v*)((const u16*)p + i);
    }
    return r;
}
template<bool FP32>
__device__ __forceinline__ void st1(void* p, size_t i, float v) {
    if (FP32) ((float*)p)[i] = v;
    else      ((u16*)p)[i] = f2us(v);
}

#define LDS_BYTES 160768

// LDS layout (bytes):
//   [0,      51200)  Ks  : K head block, local flat (Kblk[d][k] = Ks[d*400+k])
//   [51200, 104448)  Vs  : V as [416][64] bf16; rows 400..415 zeroed (K-pad)
//   [104448,136448)  Sc  : scores [20][400] fp32
//   [136448,139008)  Qcb : Q chunk [20][64] bf16
//   [139008,155648)  Pb  : probs  [20][416] bf16 (cols 400..415 zero)
//   [155648,160768)  Vl  : vals chunk [20][64] fp32
//   Phase-A overlay: Xs = [40][640] bf16 at 104448 (spans Sc+Qcb+Pb exactly)

template<bool FP32>
__global__ __launch_bounds__(256, 1)
void mha_fused(const void* __restrict__ x,
               const void* __restrict__ Wq, const void* __restrict__ Wk,
               const void* __restrict__ Wv,
               const void* __restrict__ gamma, const void* __restrict__ beta,
               void* __restrict__ out)
{
    // --- dtype guard: gamma==1.0 everywhere; low u16 of fp32 1.0f is 0 ---
    const bool buf_fp32 = (((const u16*)gamma)[0] == (u16)0);
    if (buf_fp32 != FP32) return;

    extern __shared__ char smem[];
    u16*   Ks  = (u16*)(smem);
    u16*   Vs  = (u16*)(smem + 51200);
    float* Sc  = (float*)(smem + 104448);
    u16*   Qcb = (u16*)(smem + 136448);
    u16*   Pb  = (u16*)(smem + 139008);
    float* Vl  = (float*)(smem + 155648);
    u16*   Xs  = (u16*)(smem + 104448);   // phase-A overlay

    const int    bh   = blockIdx.x;          // 0..639
    const size_t base = (size_t)bh * 25600;  // flat elem offset of head block
    const int    t    = threadIdx.x;
    const int    lane = t & 63;
    const int    w    = t >> 6;              // wave 0..3
    const int    l15  = lane & 15;
    const int    quad = lane >> 4;

    // ---- A0: stage 40 x-rows as bf16 + zero V pad rows ----
    for (int i = t; i < 3200; i += 256)
        *(s8v*)(Xs + i * 8) = ld8<FP32>(x, base + (size_t)i * 8);
    for (int i = t; i < 1024; i += 256) Vs[25600 + i] = 0;  // V rows 400..415
    __syncthreads();

    // ---- A1: Q,K,V = Xs[40x640] @ W^T via MFMA 16x16x32 ----
    // M-tiles {0,16,24}: rows 24..31 duplicated (same wave, identical values).
    // Wave w owns N-tiles nt = w+4*ni.
    {
        const int M0[3] = {0, 16, 24};
        for (int z = 0; z < 3; ++z) {
            const void* W = (z == 0) ? Wq : (z == 1) ? Wk : Wv;
            f4v acc[3][10];
            #pragma unroll
            for (int a = 0; a < 3; ++a)
                #pragma unroll
                for (int b = 0; b < 10; ++b) acc[a][b] = (f4v){0.f, 0.f, 0.f, 0.f};

            for (int k0 = 0; k0 < 640; k0 += 32) {
                s8v afr[3];
                #pragma unroll
                for (int mt = 0; mt < 3; ++mt)   // A[m=l15][k=quad*8+j]
                    afr[mt] = *(const s8v*)(Xs + (M0[mt] + l15) * 640 + k0 + quad * 8);
                #pragma unroll
                for (int ni = 0; ni < 10; ++ni) {
                    const int nt = w + ni * 4;
                    // B[k][n] = W[n][k]: row (nt*16+l15), 8 contiguous elems
                    s8v bfr = ld8<FP32>(W, (size_t)(nt * 16 + l15) * 640 + k0 + quad * 8);
                    #pragma unroll
                    for (int mt = 0; mt < 3; ++mt)
                        acc[mt][ni] = __builtin_amdgcn_mfma_f32_16x16x32_bf16(
                            afr[mt], bfr, acc[mt][ni], 0, 0, 0);
                }
            }
            #pragma unroll
            for (int mt = 0; mt < 3; ++mt)
                #pragma unroll
                for (int ni = 0; ni < 10; ++ni) {
                    const int oc = (w + ni * 4) * 16 + l15;
                    #pragma unroll
                    for (int i = 0; i < 4; ++i) {   // D[row=quad*4+i][col=l15]
                        const int r = M0[mt] + quad * 4 + i;   // local row 0..39
                        const float v = acc[mt][ni][i];
                        if (z == 0)      st1<FP32>(out, base + (size_t)r * 640 + oc, v);
                        else if (z == 1) Ks[r * 640 + oc] = f2us(v);  // == Kblk[d][k]
                        else             Vs[r * 640 + oc] = f2us(v);  // == Vblk[k][d]
                    }
                }
        }
    }
    __syncthreads();   // Ks/Vs visible; Q global stores drained

    // ---- B: 20 chunks of 20 queries; attention + fused residual LayerNorm ----
    const int M0b[2] = {0, 4};   // 20 = 16 + overlapped 4..19
    for (int qc = 0; qc < 20; ++qc) {
        // B1: Q chunk from this block's own out range (overwritten at B6)
        if (t < 160)
            *(s8v*)(Qcb + t * 8) = ld8<FP32>(out, base + (size_t)qc * 1280 + t * 8);
        __syncthreads();

        // B2: Sc[q][k] = (Qc @ Kblk)/8
        for (int nt = w; nt < 25; nt += 4) {
            #pragma unroll
            for (int mt = 0; mt < 2; ++mt) {
                f4v acc = (f4v){0.f, 0.f, 0.f, 0.f};
                #pragma unroll
                for (int kq = 0; kq < 2; ++kq) {
                    s8v a = *(const s8v*)(Qcb + (M0b[mt] + l15) * 64 + kq * 32 + quad * 8);
                    s8v b;   // B[k][n] = Ks[k*400 + n] (stride-400 gather)
                    #pragma unroll
                    for (int j = 0; j < 8; ++j)
                        b[j] = (short)Ks[(kq * 32 + quad * 8 + j) * 400 + nt * 16 + l15];
                    acc = __builtin_amdgcn_mfma_f32_16x16x32_bf16(a, b, acc, 0, 0, 0);
                }
                #pragma unroll
                for (int i = 0; i < 4; ++i)
                    Sc[(M0b[mt] + quad * 4 + i) * 400 + nt * 16 + l15] = acc[i] * 0.125f;
            }
        }
        __syncthreads();

        // B3: softmax; wave w owns rows q = w + 4*qi
        #pragma unroll
        for (int qi = 0; qi < 5; ++qi) {
            const int q = w + qi * 4;
            float m = -INFINITY;
            for (int c = lane; c < 400; c += 64) m = fmaxf(m, Sc[q * 400 + c]);
            #pragma unroll
            for (int off = 32; off; off >>= 1) m = fmaxf(m, __shfl_xor(m, off));
            float s = 0.f;
            for (int c = lane; c < 400; c += 64) {
                const float e = __expf(Sc[q * 400 + c] - m);
                Sc[q * 400 + c] = e; s += e;
            }
            #pragma unroll
            for (int off = 32; off; off >>= 1) s += __shfl_xor(s, off);
            const float inv = 1.f / s;
            for (int c = lane; c < 400; c += 64) Sc[q * 400 + c] *= inv;
        }
        __syncthreads();

        // B4: Pb = bf16(P), K-padded to 416 with zeros
        for (int i = t; i < 20 * 416; i += 256) {
            const int r = i / 416, c = i - r * 416;
            Pb[i] = (c < 400) ? f2us(Sc[r * 400 + c]) : (u16)0;
        }
        __syncthreads();

        // B5: vals = Pb[20x416] @ Vs[416x64] (V rows 400..415 zero)
        {
            const int nt = w;   // 4 N-tiles of 16, one per wave
            #pragma unroll
            for (int mt = 0; mt < 2; ++mt) {
                f4v acc = (f4v){0.f, 0.f, 0.f, 0.f};
                for (int k0 = 0; k0 < 416; k0 += 32) {
                    s8v a = *(const s8v*)(Pb + (M0b[mt] + l15) * 416 + k0 + quad * 8);
                    s8v b;   // B[k][n] = Vs[k*64 + n] (stride-64 gather)
                    #pragma unroll
                    for (int j = 0; j < 8; ++j)
                        b[j] = (short)Vs[(k0 + quad * 8 + j) * 64 + nt * 16 + l15];
                    acc = __builtin_amdgcn_mfma_f32_16x16x32_bf16(a, b, acc, 0, 0, 0);
                }
                #pragma unroll
                for (int i = 0; i < 4; ++i)
                    Vl[(M0b[mt] + quad * 4 + i) * 64 + nt * 16 + l15] = acc[i];
            }
        }
        __syncthreads();

        // B6: chunk = exactly 2 LayerNorm rows; waves 0,1 do residual + LN
        if (w < 2) {
            const int grow = bh * 40 + qc * 2 + w;   // global row in [25600,640]
            float y[10], s = 0.f, ss = 0.f;
            #pragma unroll
            for (int c = 0; c < 10; ++c) {
                const int col = lane + 64 * c;
                const float v = Vl[w * 640 + col] + ld1<FP32>(x, (size_t)grow * 640 + col);
                y[c] = v; s += v; ss += v * v;
            }
            #pragma unroll
            for (int off = 32; off; off >>= 1) {
                s += __shfl_xor(s, off); ss += __shfl_xor(ss, off);
            }
            const float mu = s * (1.f / 640.f);
            float var = ss * (1.f / 640.f) - mu * mu;
            var = fmaxf(var, 0.f);
            const float rs = rsqrtf(var + 1e-5f);
            #pragma unroll
            for (int c = 0; c < 10; ++c) {
                const int col = lane + 64 * c;
                const float o = (y[c] - mu) * rs * ld1<FP32>(gamma, col) + ld1<FP32>(beta, col);
                st1<FP32>(out, (size_t)grow * 640 + col, o);
            }
        }
        __syncthreads();
    }
}

// ---------------------------------------------------------------------------
extern "C" void kernel_launch(void* const* d_in, const int* in_sizes, int n_in,
                              void* d_out, int out_size, void* d_ws, size_t ws_size,
                              hipStream_t stream)
{
    const void* x     = d_in[0];
    const void* Wq    = d_in[1];
    const void* Wk    = d_in[2];
    const void* Wv    = d_in[3];
    const void* gamma = d_in[4];
    const void* beta  = d_in[5];
    (void)d_ws; (void)ws_size; (void)in_sizes; (void)n_in; (void)out_size;

    // >64 KiB dynamic LDS: raise the cap for both instantiations (host-side,
    // idempotent, graph-capture-safe).
    hipFuncSetAttribute(reinterpret_cast<const void*>(&mha_fused<false>),
                        hipFuncAttributeMaxDynamicSharedMemorySize, LDS_BYTES);
    hipFuncSetAttribute(reinterpret_cast<const void*>(&mha_fused<true>),
                        hipFuncAttributeMaxDynamicSharedMemorySize, LDS_BYTES);

    // Launch both dtype variants; the one whose template param mismatches the
    // on-device sniff (gamma[0] low bytes) exits immediately.
    mha_fused<false><<<640, 256, LDS_BYTES, stream>>>(x, Wq, Wk, Wv, gamma, beta, d_out);
    mha_fused<true ><<<640, 256, LDS_BYTES, stream>>>(x, Wq, Wk, Wv, gamma, beta, d_out);
}

// Round 5
// 759.090 us; speedup vs baseline: 2.4207x; 2.4207x over previous
//
#include <hip/hip_runtime.h>
#include <hip/hip_bf16.h>

// Problem: N=25600 rows, D=640, B=64 batches, H=10 heads, dk=64, SEQ=400.
// head_splitter is a RAW RESHAPE: head (b,h) owns flat range [bh*25600,+25600)
// == x-rows [bh*40,+40) x all 640 cols. Qblk/Vblk = range viewed [400][64];
// Kblk = same range viewed [64][400]. vals flat order == out flat order
// -> fully block-private pipeline per head. Buffers are fp32 (proven R4).
//
// R4 counters: MfmaUtil 2.6%, VALUBusy 12%, Occ 10%, 7.2e7 bank conflicts ->
// latency-bound: 4 waves/CU + scalar ds_read_u16 gathers. This round:
// 16 waves/block (1024 thr, <=128 VGPR), transposed LDS layouts so every
// MFMA fragment is one ds_read_b128 on conflict-free padded strides, Q via
// global round-trip (bf16 ws, fp32-out fallback), weights pre-cvt to bf16.

typedef unsigned short u16;
typedef short s8v __attribute__((ext_vector_type(8)));   // 8 bf16 (4 VGPRs)
typedef float f4v __attribute__((ext_vector_type(4)));   // MFMA accumulator
typedef u16  u4v __attribute__((ext_vector_type(4)));    // 4 bf16 (8B store)

__device__ __forceinline__ float us2f(u16 u) {
    union { float f; unsigned int i; } v; v.i = ((unsigned int)u) << 16; return v.f;
}
__device__ __forceinline__ u16 f2us(float f) {
    __hip_bfloat16 h = __float2bfloat16(f);
    return *reinterpret_cast<u16*>(&h);
}
__device__ __forceinline__ s8v ld8f(const float* p) {   // 8 fp32 -> bf16x8
    const float4 a = ((const float4*)p)[0], b = ((const float4*)p)[1];
    s8v r;
    r[0] = (short)f2us(a.x); r[1] = (short)f2us(a.y);
    r[2] = (short)f2us(a.z); r[3] = (short)f2us(a.w);
    r[4] = (short)f2us(b.x); r[5] = (short)f2us(b.y);
    r[6] = (short)f2us(b.z); r[7] = (short)f2us(b.w);
    return r;
}

// LDS map (bytes):                                   size
//   Kt  @      0 : [400][72]  bf16  (K^T, per-head) 57600
//   Vt  @  57600 : [64][424]  bf16  (V^T, keys padded->0 at 400..423) 54272
//   Xs  @ 111872 : [40][648]  bf16  (x rows, phase A only)            51840
//   -- phase B overlay of Xs area --
//   Pb  @ 111872 : [40][424]  bf16  (scores -> unnorm exp)            33920
//   Vl  @ 145792 : [2560]     fp32  (E@V chunk, == 4 out rows)        10240
//   rs_ @ 156032 : [40]       fp32  (softmax denominators)              160
#define LDS_BYTES 163712

// MODE 0: W bf16 + Q bf16 in ws (needs ws >= 35225600 B)
// MODE 1: W fp32 from global, Q fp32 round-trip through d_out (zero ws)
template<int MODE>
__global__ __launch_bounds__(1024, 4)
void mha(const float* __restrict__ x,
         const float* __restrict__ Wq, const float* __restrict__ Wk,
         const float* __restrict__ Wv,
         const float* __restrict__ gamma, const float* __restrict__ beta,
         float* __restrict__ out,
         const u16* __restrict__ Wb, u16* __restrict__ Qb)
{
    extern __shared__ char smem[];
    u16*   Kt  = (u16*)(smem);
    u16*   Vt  = (u16*)(smem + 57600);
    u16*   Xs  = (u16*)(smem + 111872);
    u16*   Pb  = (u16*)(smem + 111872);
    float* Vl  = (float*)(smem + 145792);
    float* rs_ = (float*)(smem + 156032);

    const int    bh   = blockIdx.x;          // 0..639
    const size_t base = (size_t)bh * 25600;  // head's flat elem offset
    const int    t    = threadIdx.x;
    const int    lane = t & 63;
    const int    w    = t >> 6;              // wave 0..15
    const int    l15  = lane & 15;
    const int    quad = lane >> 4;

    // ---- A0: x rows -> Xs bf16 (row stride 648); zero Vt key-pad cols ----
    for (int i = t; i < 6400; i += 1024) {           // 6400 float4 groups
        const int row = i / 160, col = (i % 160) * 4;
        const float4 v = *(const float4*)(x + base + row * 640 + col);
        *(u4v*)(Xs + row * 648 + col) =
            (u4v){f2us(v.x), f2us(v.y), f2us(v.z), f2us(v.w)};
    }
    for (int i = t; i < 64 * 24; i += 1024)          // Vt cols 400..423 = 0
        Vt[(i / 24) * 424 + 400 + (i % 24)] = 0;
    __syncthreads();

    // ---- A1: Q,K,V = Xs[40x640] @ W^T, MFMA 16x16x32 ----
    // M-tiles {0,16,24} (rows 24..31 duplicated -> identical values, benign).
    // Wave w owns N-tiles {w, w+16, w+32<40}. Q first (global stores fly
    // during K/V); K/V epilogues scatter into transposed LDS layouts.
    {
        const int M0a[3] = {0, 16, 24};
        int nts[3], nnt = 0;
        for (int nt = w; nt < 40; nt += 16) nts[nnt++] = nt;

        for (int zi = 0; zi < 3; ++zi) {   // 0=Q 1=K 2=V
            const float* Wsrc = (zi == 0) ? Wq : (zi == 1) ? Wk : Wv;
            f4v acc[3][3];
            #pragma unroll
            for (int a = 0; a < 3; ++a)
                #pragma unroll
                for (int b = 0; b < 3; ++b) acc[a][b] = (f4v){0.f,0.f,0.f,0.f};

            for (int k0 = 0; k0 < 640; k0 += 32) {
                s8v afr[3];
                #pragma unroll
                for (int mt = 0; mt < 3; ++mt)
                    afr[mt] = *(const s8v*)(Xs + (M0a[mt] + l15) * 648 + k0 + quad * 8);
                #pragma unroll
                for (int nk = 0; nk < 3; ++nk) {
                    if (nk >= nnt) break;
                    const int nt = nts[nk];
                    s8v bfr;
                    if (MODE == 0)
                        bfr = *(const s8v*)(Wb + (size_t)zi * 409600
                                            + (nt * 16 + l15) * 640 + k0 + quad * 8);
                    else
                        bfr = ld8f(Wsrc + (size_t)(nt * 16 + l15) * 640 + k0 + quad * 8);
                    #pragma unroll
                    for (int mt = 0; mt < 3; ++mt)
                        acc[nk][mt] = __builtin_amdgcn_mfma_f32_16x16x32_bf16(
                            afr[mt], bfr, acc[nk][mt], 0, 0, 0);
                }
            }
            // epilogue: D[row=quad*4+i][col=l15]
            #pragma unroll
            for (int nk = 0; nk < 3; ++nk) {
                if (nk >= nnt) break;
                #pragma unroll
                for (int mt = 0; mt < 3; ++mt)
                    #pragma unroll
                    for (int i = 0; i < 4; ++i) {
                        const int r  = M0a[mt] + quad * 4 + i;   // local x-row
                        const int oc = nts[nk] * 16 + l15;       // col
                        const int f  = r * 640 + oc;             // local flat
                        const float v = acc[nk][mt][i];
                        if (zi == 0) {
                            if (MODE == 0) Qb[base + f] = f2us(v);
                            else           out[base + f] = v;
                        } else if (zi == 1) {
                            const int d = f / 400, key = f - d * 400;
                            Kt[key * 72 + d] = f2us(v);          // K^T
                        } else {
                            Vt[(f & 63) * 424 + (f >> 6)] = f2us(v);  // V^T
                        }
                    }
            }
        }
    }
    __syncthreads();   // Kt/Vt visible; Q stores drained (vmcnt before barrier)

    // ---- B: 10 chunks of 40 queries (= 4 LayerNorm rows each) ----
    const int M0b[3] = {0, 16, 24};
    for (int qc = 0; qc < 10; ++qc) {
        // B2: scores.  Wave w: key-tiles {w, w+16<25}. A from global Q (L2).
        for (int nt = w; nt < 25; nt += 16) {
            s8v bfr[2];
            #pragma unroll
            for (int kq = 0; kq < 2; ++kq)
                bfr[kq] = *(const s8v*)(Kt + (nt * 16 + l15) * 72 + kq * 32 + quad * 8);
            #pragma unroll
            for (int mt = 0; mt < 3; ++mt) {
                f4v acc = (f4v){0.f, 0.f, 0.f, 0.f};
                #pragma unroll
                for (int kq = 0; kq < 2; ++kq) {
                    const size_t qoff = base + (size_t)qc * 2560
                                      + (M0b[mt] + l15) * 64 + kq * 32 + quad * 8;
                    s8v a = (MODE == 0) ? *(const s8v*)(Qb + qoff) : ld8f(out + qoff);
                    acc = __builtin_amdgcn_mfma_f32_16x16x32_bf16(a, bfr[kq], acc, 0, 0, 0);
                }
                #pragma unroll
                for (int i = 0; i < 4; ++i)
                    Pb[(M0b[mt] + quad * 4 + i) * 424 + nt * 16 + l15] =
                        f2us(acc[i] * 0.125f);               // 1/sqrt(64)
            }
        }
        __syncthreads();

        // B3: softmax rows {w, w+16, w+32<40}; store unnormalized exp (bf16)
        for (int q = w; q < 40; q += 16) {
            float sv[7], m = -1e30f;
            #pragma unroll
            for (int ii = 0; ii < 7; ++ii) {
                const int c = lane + ii * 64;
                sv[ii] = (c < 400) ? us2f(Pb[q * 424 + c]) : -1e30f;
                m = fmaxf(m, sv[ii]);
            }
            #pragma unroll
            for (int off = 32; off; off >>= 1) m = fmaxf(m, __shfl_xor(m, off));
            float s = 0.f;
            #pragma unroll
            for (int ii = 0; ii < 7; ++ii) {
                const int c = lane + ii * 64;
                const float e = (c < 400) ? __expf(sv[ii] - m) : 0.f;
                s += e;
                if (c < 424) Pb[q * 424 + c] = f2us(e);
            }
            #pragma unroll
            for (int off = 32; off; off >>= 1) s += __shfl_xor(s, off);
            if (lane == 0) rs_[q] = s;
        }
        __syncthreads();

        // B5: E @ V.  12 (mt,nt) combos on waves 0..11; K=416 (pads are 0).
        if (w < 12) {
            const int mt = w >> 2, nt = w & 3;
            f4v acc = (f4v){0.f, 0.f, 0.f, 0.f};
            for (int k0 = 0; k0 < 416; k0 += 32) {
                s8v a = *(const s8v*)(Pb + (M0b[mt] + l15) * 424 + k0 + quad * 8);
                s8v b = *(const s8v*)(Vt + (nt * 16 + l15) * 424 + k0 + quad * 8);
                acc = __builtin_amdgcn_mfma_f32_16x16x32_bf16(a, b, acc, 0, 0, 0);
            }
            #pragma unroll
            for (int i = 0; i < 4; ++i)
                Vl[(M0b[mt] + quad * 4 + i) * 64 + nt * 16 + l15] = acc[i];
        }
        __syncthreads();

        // B6: 4 output rows; waves 0..3: vals/l + x -> LayerNorm -> out (fp32)
        if (w < 4) {
            const int    r    = qc * 4 + w;            // local x-row
            const size_t grow = base + (size_t)r * 640;
            float y[10], s = 0.f, ss = 0.f;
            #pragma unroll
            for (int ci = 0; ci < 10; ++ci) {
                const int col = lane + 64 * ci;
                const float v = Vl[w * 640 + col] / rs_[w * 10 + ci] + x[grow + col];
                y[ci] = v; s += v; ss += v * v;
            }
            #pragma unroll
            for (int off = 32; off; off >>= 1) {
                s += __shfl_xor(s, off); ss += __shfl_xor(ss, off);
            }
            const float mu = s * (1.f / 640.f);
            float var = ss * (1.f / 640.f) - mu * mu;
            var = fmaxf(var, 0.f);
            const float rstd = rsqrtf(var + 1e-5f);
            #pragma unroll
            for (int ci = 0; ci < 10; ++ci) {
                const int col = lane + 64 * ci;
                out[grow + col] = (y[ci] - mu) * rstd * gamma[col] + beta[col];
            }
        }
        // no barrier needed: next B2 writes Pb only (disjoint from Vl/rs_);
        // next writers of rs_/Vl are B3/B5, both >=1 barrier away.
    }
}

// ---- K0: convert the three weight matrices to bf16 in ws (MODE 0) ----
__global__ __launch_bounds__(256)
void wconv(const float* __restrict__ Wq, const float* __restrict__ Wk,
           const float* __restrict__ Wv, u16* __restrict__ Wb)
{
    const int g = blockIdx.x * 256 + threadIdx.x;    // 153600 groups of 8
    const float* src = (g < 51200) ? Wq : (g < 102400) ? Wk : Wv;
    const int rem = g % 51200;
    *(s8v*)(Wb + (size_t)g * 8) = ld8f(src + (size_t)rem * 8);
}

// ---------------------------------------------------------------------------
extern "C" void kernel_launch(void* const* d_in, const int* in_sizes, int n_in,
                              void* d_out, int out_size, void* d_ws, size_t ws_size,
                              hipStream_t stream)
{
    const float* x     = (const float*)d_in[0];
    const float* Wq    = (const float*)d_in[1];
    const float* Wk    = (const float*)d_in[2];
    const float* Wv    = (const float*)d_in[3];
    const float* gamma = (const float*)d_in[4];
    const float* beta  = (const float*)d_in[5];
    float* out = (float*)d_out;
    (void)in_sizes; (void)n_in; (void)out_size;

    // ws layout (MODE 0): Wb bf16 [3][640][640] = 2457600 B | Qb bf16 = 32768000 B
    const bool ws_ok = (ws_size >= (size_t)(2457600 + 32768000));
    u16* Wb = (u16*)d_ws;
    u16* Qb = Wb + 1228800;

    hipFuncSetAttribute(reinterpret_cast<const void*>(&mha<0>),
                        hipFuncAttributeMaxDynamicSharedMemorySize, LDS_BYTES);
    hipFuncSetAttribute(reinterpret_cast<const void*>(&mha<1>),
                        hipFuncAttributeMaxDynamicSharedMemorySize, LDS_BYTES);

    if (ws_ok) {
        wconv<<<600, 256, 0, stream>>>(Wq, Wk, Wv, Wb);
        mha<0><<<640, 1024, LDS_BYTES, stream>>>(x, Wq, Wk, Wv, gamma, beta, out, Wb, Qb);
    } else {
        mha<1><<<640, 1024, LDS_BYTES, stream>>>(x, Wq, Wk, Wv, gamma, beta, out, Wb, Qb);
    }
}